// Round 22
// baseline (1261.152 us; speedup 1.0000x reference)
//
#include <hip/hip_runtime.h>
#include <hip/hip_bf16.h>

// GraphProcessor: S=16,B=64,C=128,H=W=11,P=121, 3 iterations.
// Round 22: prep launches merged (19->7); final output fused into last gru_fused.
#define S_   16
#define B_   64
#define SBn  1024
#define C_   128
#define P_   121
#define CP_  15488
#define LTS  17408   // 128*136
static const long NEl = 15859712L; // SBn*CP_

typedef __hip_bfloat16 bf16t;
typedef __attribute__((ext_vector_type(8))) short bf16x8;
typedef __attribute__((ext_vector_type(4))) float f32x4;
typedef __attribute__((ext_vector_type(4))) unsigned short us4;

__device__ __forceinline__ float ldb(const bf16t* p){ return __bfloat162float(*p); }
__device__ __forceinline__ float b2f(unsigned short u){ unsigned x=((unsigned)u)<<16; float f; __builtin_memcpy(&f,&x,4); return f; }
__device__ __forceinline__ unsigned short f2bu(float v){ __hip_bfloat16 b=__float2bfloat16(v); unsigned short u; __builtin_memcpy(&u,&b,2); return u; }
__device__ __forceinline__ float ldin(const void* s, long i, int f){
    return f ? ((const float*)s)[i] : b2f(((const unsigned short*)s)[i]);
}

// ---------- dtype detect ----------
__global__ void detect_kernel(const unsigned short* __restrict__ x, int* __restrict__ flag){
    if(blockIdx.x==0 && threadIdx.x==0){
        int crazy=0;
        for(int i=0;i<512;i++){
            unsigned e=(x[i]>>7)&0xFF;
            if(e!=0 && (e<64 || e>191)) crazy++;
        }
        *flag=(crazy>40)?1:0;
    }
}

__global__ __launch_bounds__(256) void cvtT_kernel(bf16t* __restrict__ hT, const void* __restrict__ x, const int* __restrict__ flag){
    __shared__ bf16t tl[CP_];
    int sb=blockIdx.x, t=threadIdx.x; int f=*flag;
    for(int i=t;i<CP_;i+=256)
        tl[i]=__float2bfloat16(ldin(x,(long)sb*CP_+i,f));
    __syncthreads();
    bf16t* ho=hT+(size_t)sb*CP_;
    for(int j=t;j<CP_;j+=256){
        int p=j>>7, c=j&127;
        ho[j]=tl[c*P_+p];
    }
}

// ---------- merged small-prep: q/k/v weight tiles, wgT, gamT/betT, all biases+scalars ----------
__global__ __launch_bounds__(256) void prep_small(
    bf16t* __restrict__ wqT, bf16t* __restrict__ wkT, bf16t* __restrict__ wvT, float* __restrict__ wgT,
    float* __restrict__ gamT, float* __restrict__ betT,
    float* __restrict__ bqf, float* __restrict__ bkf, float* __restrict__ bvf,
    float* __restrict__ bzrf, float* __restrict__ bhf, float* __restrict__ bgf2,
    float* __restrict__ alphaf, float* __restrict__ weightf,
    const void* dwq, const void* dwk, const void* dwv, const void* dwg,
    const void* dgam, const void* dbet,
    const void* dbq, const void* dbk, const void* dbv, const void* dbzr, const void* dbh, const void* dbg,
    const void* dal, const void* dwt,
    const int* __restrict__ flag)
{
    int idx=blockIdx.x*256+threadIdx.x;
    int f=*flag;
    if(idx<16384){
        int r=idx&31, oc=(idx>>5)&127, icb=idx>>12;
        wqT[idx]=__float2bfloat16(ldin(dwq,(long)oc*C_+icb*32+r,f));
    }else if(idx<32768){
        int l=idx-16384; int r=l&31, oc=(l>>5)&127, icb=l>>12;
        wkT[l]=__float2bfloat16(ldin(dwk,(long)oc*C_+icb*32+r,f));
    }else if(idx<49152){
        int l=idx-32768; int r=l&31, oc=(l>>5)&127, icb=l>>12;
        wvT[l]=__float2bfloat16(ldin(dwv,(long)oc*C_+icb*32+r,f));
    }else if(idx<65536){
        int l=idx-49152; int k=l>>7, c=l&127;
        wgT[l]=ldin(dwg,(long)c*C_+k,f);
    }else if(idx<81024){
        int l=idx-65536; int c=l/P_, p=l-c*P_;
        gamT[p*C_+c]=ldin(dgam,l,f);
    }else if(idx<96512){
        int l=idx-81024; int c=l/P_, p=l-c*P_;
        betT[p*C_+c]=ldin(dbet,l,f);
    }else if(idx<97442){
        int l=idx-96512;
        if(l<128)       bqf[l]      =ldin(dbq,l,f);
        else if(l<256)  bkf[l-128]  =ldin(dbk,l-128,f);
        else if(l<384)  bvf[l-256]  =ldin(dbv,l-256,f);
        else if(l<640)  bzrf[l-384] =ldin(dbzr,l-384,f);
        else if(l<768)  bhf[l-640]  =ldin(dbh,l-640,f);
        else if(l<896)  bgf2[l-768] =ldin(dbg,l-768,f);
        else if(l==896) alphaf[0]   =ldin(dal,0,f);
        else if(l==897) weightf[0]  =ldin(dwt,0,f);
    }
}

__global__ __launch_bounds__(128) void prep_msg_kernel(float* __restrict__ W2, float* __restrict__ b2l, float* __restrict__ b2r,
        const void* __restrict__ wlin, const void* __restrict__ wmsg, const void* __restrict__ bmsg, const int* __restrict__ flag){
    int d=blockIdx.x, c=threadIdx.x; int f=*flag;
    float acc=0.f;
    for(int o2=0;o2<C_;o2++) acc += ldin(wlin,(long)d*C_+o2,f)*ldin(wmsg,(long)o2*(C_+1)+c,f);
    W2[d*C_+c]=acc;
    if(c<2){
        float e=(c==0)?1.f:-1.f; float a=0.f;
        for(int o2=0;o2<C_;o2++) a += ldin(wlin,(long)d*C_+o2,f)*(ldin(bmsg,o2,f)+e*ldin(wmsg,(long)o2*(C_+1)+C_,f));
        if(c==0) b2l[d]=a; else b2r[d]=a;
    }
}

// ---------- 1x1 weight f32 [oc][128ic] -> tiled bf16 [icb(4)][oc(128)][32] (for W2) ----------
__global__ void prep_w1tf(bf16t* __restrict__ dst, const float* __restrict__ src){
    int idx=blockIdx.x*blockDim.x+threadIdx.x;
    if(idx>=16384) return;
    int r=idx&31, oc=(idx>>5)&127, icb=idx>>12;
    dst[idx]=__float2bfloat16(src[(long)oc*C_+icb*32+r]);
}

__global__ void prep_w3t(bf16t* __restrict__ dst, const void* __restrict__ src, const int* __restrict__ flag, int OC){
    int idx=blockIdx.x*blockDim.x+threadIdx.x;
    int tot=OC*2304;
    if(idx>=tot) return;
    int r=idx&31; int rest=idx>>5; int oc=rest%OC; int g2=rest/OC; int icb=g2&7, tap=g2>>3;
    float v=ldin(src,((long)(oc*256+icb*32+r))*9+tap,*flag);
    dst[idx]=__float2bfloat16(v);
}

// ---------- 128x128x128 GEMM tile, 8 waves (2 ocr x 4 pcr), B from registers ----------
__device__ __forceinline__ void gemm24r(f32x4 (&acc)[4][2],
    const bf16t* __restrict__ Wt, const bf16x8 (&hreg)[4][2],
    int ocr,int l15,int kg)
{
    #pragma unroll
    for(int i=0;i<4;i++){
        #pragma unroll
        for(int j=0;j<2;j++) acc[i][j]=(f32x4){0.f,0.f,0.f,0.f};
    }
    #pragma unroll
    for(int kc=0;kc<4;kc++){
        bf16x8 a[4];
        #pragma unroll
        for(int mt=0;mt<4;mt++) a[mt]=*(const bf16x8*)(Wt+((size_t)(kc*C_+ocr*64+mt*16+l15))*32+kg*8);
        #pragma unroll
        for(int mt=0;mt<4;mt++){
            #pragma unroll
            for(int nt=0;nt<2;nt++)
                acc[mt][nt]=__builtin_amdgcn_mfma_f32_16x16x32_bf16(a[mt],hreg[kc][nt],acc[mt][nt],0,0,0);
        }
    }
}

// ---------- dual message phase ----------
__device__ __forceinline__ void msg_phase2(
    f32x4 (&res)[2][8], const bf16t* __restrict__ hT, int sb0, int shift,
    const bf16t* __restrict__ W2T, const float* __restrict__ b2e,
    const float* __restrict__ wgT, const float* __restrict__ bgf, float w1m,
    const bf16x8 (&areg)[2][4],
    bf16t (*LA)[LTS], bf16t (*LB)[LTS], float (*fl)[256],
    int t,int w,int l15,int kg,int ocr,int pcr)
{
    __syncthreads();
    int m0=w*16;
    #pragma unroll
    for(int io=0;io<2;io++){
        const bf16t* hsp=hT+(size_t)(sb0+io+shift)*CP_;
        bf16x8 hregS[4][2];
        #pragma unroll
        for(int kc=0;kc<4;kc++){
            #pragma unroll
            for(int nt=0;nt<2;nt++)
                hregS[kc][nt]=*(const bf16x8*)(hsp+(size_t)(pcr*32+nt*16+l15)*C_+kc*32+kg*8);
        }
        f32x4 acc[4][2];
        gemm24r(acc,W2T,hregS,ocr,l15,kg);
        #pragma unroll
        for(int mt=0;mt<4;mt++){
            int oc0=ocr*64+mt*16+kg*4;
            #pragma unroll
            for(int nt=0;nt<2;nt++){
                int p=pcr*32+nt*16+l15;
                us4 pk;
                #pragma unroll
                for(int r=0;r<4;r++){
                    float v=acc[mt][nt][r]+b2e[oc0+r];
                    pk[r]=f2bu(v);
                    LB[io][(oc0+r)*136+p]=__float2bfloat16(p<P_? v : 0.f);
                }
                *(us4*)(LA[io]+p*136+oc0)=pk;
            }
        }
    }
    __syncthreads();
    f32x4 s[2][8];
    #pragma unroll
    for(int io=0;io<2;io++){
        #pragma unroll
        for(int nt=0;nt<8;nt++) s[io][nt]=(f32x4){0.f,0.f,0.f,0.f};
        #pragma unroll
        for(int kc=0;kc<4;kc++){
            #pragma unroll
            for(int nt=0;nt<8;nt++){
                bf16x8 b=*(const bf16x8*)(LA[io]+(size_t)(nt*16+l15)*136+kc*32+kg*8);
                s[io][nt]=__builtin_amdgcn_mfma_f32_16x16x32_bf16(areg[io][kc],b,s[io][nt],0,0,0);
            }
        }
        if(l15>=9){
            #pragma unroll
            for(int r=0;r<4;r++) s[io][7][r]=-3.0e38f;
        }
        #pragma unroll
        for(int r=0;r<4;r++){
            float mx=s[io][0][r];
            #pragma unroll
            for(int nt=1;nt<8;nt++) mx=fmaxf(mx,s[io][nt][r]);
            #pragma unroll
            for(int o=1;o<16;o<<=1) mx=fmaxf(mx,__shfl_xor(mx,o));
            float sm=0.f;
            #pragma unroll
            for(int nt=0;nt<8;nt++){ float e=__expf(s[io][nt][r]-mx); s[io][nt][r]=e; sm+=e; }
            #pragma unroll
            for(int o=1;o<16;o<<=1) sm+=__shfl_xor(sm,o);
            float rs=1.f/sm;
            #pragma unroll
            for(int nt=0;nt<8;nt++) s[io][nt][r]*=rs;
        }
    }
    __syncthreads();
    #pragma unroll
    for(int io=0;io<2;io++){
        #pragma unroll
        for(int r=0;r<4;r++){
            int pr=m0+kg*4+r;
            #pragma unroll
            for(int nt=0;nt<8;nt++) LA[io][pr*136+nt*16+l15]=__float2bfloat16(s[io][nt][r]);
        }
    }
    __syncthreads();
    f32x4 o[2][8];
    #pragma unroll
    for(int io=0;io<2;io++){
        #pragma unroll
        for(int nt=0;nt<8;nt++) o[io][nt]=(f32x4){0.f,0.f,0.f,0.f};
        #pragma unroll
        for(int jc=0;jc<4;jc++){
            bf16x8 a=*(const bf16x8*)(LB[io]+(size_t)(m0+l15)*136+jc*32+kg*8);
            #pragma unroll
            for(int nt=0;nt<8;nt++){
                bf16x8 b=*(const bf16x8*)(LA[io]+(size_t)(nt*16+l15)*136+jc*32+kg*8);
                o[io][nt]=__builtin_amdgcn_mfma_f32_16x16x32_bf16(a,b,o[io][nt],0,0,0);
            }
        }
    }
    int c0=m0+kg*4;
    #pragma unroll
    for(int io=0;io<2;io++){
        #pragma unroll
        for(int r=0;r<4;r++){
            float sm=0.f;
            #pragma unroll
            for(int nt=0;nt<8;nt++){ float v=o[io][nt][r]; if(nt==7&&l15>8) v=0.f; sm+=v; }
            sm+=__shfl_xor(sm,1); sm+=__shfl_xor(sm,2); sm+=__shfl_xor(sm,4); sm+=__shfl_xor(sm,8);
            if(l15==0) fl[io][c0+r]=sm*(1.f/121.f);
        }
    }
    __syncthreads();
    if(t<256){
        int which=t>>7, c=t&127;
        float a=bgf[c];
        #pragma unroll 8
        for(int k=0;k<C_;k++) a+=wgT[k*C_+c]*fl[which][k];
        fl[which][C_+c]=1.f/(1.f+__expf(-a));
    }
    __syncthreads();
    #pragma unroll
    for(int io=0;io<2;io++){
        float gg[4];
        #pragma unroll
        for(int r=0;r<4;r++) gg[r]=fl[io][C_+c0+r];
        #pragma unroll
        for(int nt=0;nt<8;nt++){
            #pragma unroll
            for(int r=0;r<4;r++) res[io][nt][r]+=w1m*o[io][nt][r]*gg[r];
        }
    }
}

// ---------- fused intra + msgs for a PAIR of sb, 512 threads ----------
__global__ __launch_bounds__(512) void attn2(
    bf16t* __restrict__ comb, const bf16t* __restrict__ hT,
    const bf16t* __restrict__ WqT, const bf16t* __restrict__ WkT, const bf16t* __restrict__ WvT,
    const float* __restrict__ bq, const float* __restrict__ bk, const float* __restrict__ bv,
    const bf16t* __restrict__ W2T, const float* __restrict__ b2l, const float* __restrict__ b2r,
    const float* __restrict__ wgT, const float* __restrict__ bgf,
    const float* __restrict__ alphap, const float* __restrict__ wp)
{
    __shared__ bf16t LA[2][LTS];
    __shared__ bf16t LB[2][LTS];
    __shared__ float fl[2][256];
    int sb0=(int)blockIdx.x*2, t=threadIdx.x, lane=t&63, w=t>>6;
    int l15=lane&15, kg=lane>>4;
    int ocr=w>>2, pcr=w&3;
    int m0=w*16;
    const bf16t* hp0=hT+(size_t)sb0*CP_;
    const bf16t* hp1=hp0+CP_;
    bf16x8 hreg[2][4][2];
    bf16x8 areg[2][4];
    #pragma unroll
    for(int kc=0;kc<4;kc++){
        #pragma unroll
        for(int nt=0;nt<2;nt++){
            hreg[0][kc][nt]=*(const bf16x8*)(hp0+(size_t)(pcr*32+nt*16+l15)*C_+kc*32+kg*8);
            hreg[1][kc][nt]=*(const bf16x8*)(hp1+(size_t)(pcr*32+nt*16+l15)*C_+kc*32+kg*8);
        }
        areg[0][kc]=*(const bf16x8*)(hp0+(size_t)(m0+l15)*C_+kc*32+kg*8);
        areg[1][kc]=*(const bf16x8*)(hp1+(size_t)(m0+l15)*C_+kc*32+kg*8);
    }
    #pragma unroll
    for(int io=0;io<2;io++){
        f32x4 acc[4][2];
        gemm24r(acc,WqT,hreg[io],ocr,l15,kg);
        #pragma unroll
        for(int mt=0;mt<4;mt++){
            int oc0=ocr*64+mt*16+kg*4;
            #pragma unroll
            for(int nt=0;nt<2;nt++){
                int p=pcr*32+nt*16+l15;
                us4 pk;
                #pragma unroll
                for(int r=0;r<4;r++) pk[r]=f2bu(acc[mt][nt][r]+bq[oc0+r]);
                *(us4*)(LA[io]+p*136+oc0)=pk;
            }
        }
        gemm24r(acc,WkT,hreg[io],ocr,l15,kg);
        #pragma unroll
        for(int mt=0;mt<4;mt++){
            int oc0=ocr*64+mt*16+kg*4;
            #pragma unroll
            for(int nt=0;nt<2;nt++){
                int p=pcr*32+nt*16+l15;
                us4 pk;
                #pragma unroll
                for(int r=0;r<4;r++) pk[r]=f2bu(acc[mt][nt][r]+bk[oc0+r]);
                *(us4*)(LB[io]+p*136+oc0)=pk;
            }
        }
    }
    __syncthreads();
    const float scale=0.08838834764831845f;
    f32x4 s[2][8];
    #pragma unroll
    for(int io=0;io<2;io++){
        #pragma unroll
        for(int nt=0;nt<8;nt++) s[io][nt]=(f32x4){0.f,0.f,0.f,0.f};
        #pragma unroll
        for(int kc=0;kc<4;kc++){
            bf16x8 a=*(const bf16x8*)(LA[io]+(size_t)(m0+l15)*136+kc*32+kg*8);
            #pragma unroll
            for(int nt=0;nt<8;nt++){
                bf16x8 b=*(const bf16x8*)(LB[io]+(size_t)(nt*16+l15)*136+kc*32+kg*8);
                s[io][nt]=__builtin_amdgcn_mfma_f32_16x16x32_bf16(a,b,s[io][nt],0,0,0);
            }
        }
        #pragma unroll
        for(int nt=0;nt<8;nt++){
            #pragma unroll
            for(int r=0;r<4;r++) s[io][nt][r]*=scale;
        }
        if(l15>=9){
            #pragma unroll
            for(int r=0;r<4;r++) s[io][7][r]=-3.0e38f;
        }
        #pragma unroll
        for(int r=0;r<4;r++){
            float mx=s[io][0][r];
            #pragma unroll
            for(int nt=1;nt<8;nt++) mx=fmaxf(mx,s[io][nt][r]);
            #pragma unroll
            for(int o=1;o<16;o<<=1) mx=fmaxf(mx,__shfl_xor(mx,o));
            float sm=0.f;
            #pragma unroll
            for(int nt=0;nt<8;nt++){ float e=__expf(s[io][nt][r]-mx); s[io][nt][r]=e; sm+=e; }
            #pragma unroll
            for(int o=1;o<16;o<<=1) sm+=__shfl_xor(sm,o);
            float rs=1.f/sm;
            #pragma unroll
            for(int nt=0;nt<8;nt++) s[io][nt][r]*=rs;
        }
    }
    __syncthreads();
    #pragma unroll
    for(int io=0;io<2;io++){
        f32x4 acc[4][2];
        gemm24r(acc,WvT,hreg[io],ocr,l15,kg);
        #pragma unroll
        for(int mt=0;mt<4;mt++){
            int oc0=ocr*64+mt*16+kg*4;
            #pragma unroll
            for(int nt=0;nt<2;nt++){
                int p=pcr*32+nt*16+l15;
                #pragma unroll
                for(int r=0;r<4;r++)
                    LA[io][(oc0+r)*136+p]=__float2bfloat16(p<P_? acc[mt][nt][r]+bv[oc0+r] : 0.f);
            }
        }
        #pragma unroll
        for(int r=0;r<4;r++){
            int pr=m0+kg*4+r;
            #pragma unroll
            for(int nt=0;nt<8;nt++) LB[io][pr*136+nt*16+l15]=__float2bfloat16(s[io][nt][r]);
        }
    }
    __syncthreads();
    float al=*alphap, wv=*wp, w1m=1.f-wv;
    int c0=m0+kg*4;
    f32x4 res[2][8];
    #pragma unroll
    for(int io=0;io<2;io++){
        #pragma unroll
        for(int nt=0;nt<8;nt++) res[io][nt]=(f32x4){0.f,0.f,0.f,0.f};
        #pragma unroll
        for(int jc=0;jc<4;jc++){
            bf16x8 a=*(const bf16x8*)(LA[io]+(size_t)(m0+l15)*136+jc*32+kg*8);
            #pragma unroll
            for(int nt=0;nt<8;nt++){
                bf16x8 b=*(const bf16x8*)(LB[io]+(size_t)(nt*16+l15)*136+jc*32+kg*8);
                res[io][nt]=__builtin_amdgcn_mfma_f32_16x16x32_bf16(a,b,res[io][nt],0,0,0);
            }
        }
        const bf16t* hp=(io==0)?hp0:hp1;
        #pragma unroll
        for(int nt=0;nt<8;nt++){
            int p=nt*16+l15;
            int pc=(p<P_)?p:(P_-1);
            us4 hv=*(const us4*)(hp+(size_t)pc*C_+c0);
            #pragma unroll
            for(int r=0;r<4;r++) res[io][nt][r]=wv*(al*res[io][nt][r]+b2f(hv[r]));
        }
    }
    if(sb0>=B_)
        msg_phase2(res,hT,sb0,-B_,W2T,b2l,wgT,bgf,w1m,areg,LA,LB,fl,t,w,l15,kg,ocr,pcr);
    if(sb0<SBn-B_)
        msg_phase2(res,hT,sb0, B_,W2T,b2r,wgT,bgf,w1m,areg,LA,LB,fl,t,w,l15,kg,ocr,pcr);
    __syncthreads();
    #pragma unroll
    for(int io=0;io<2;io++){
        unsigned short* tl=(unsigned short*)LA[io];
        #pragma unroll
        for(int nt=0;nt<8;nt++){
            int p=nt*16+l15;
            if(p>=P_) continue;
            us4 pk;
            #pragma unroll
            for(int r=0;r<4;r++) pk[r]=f2bu(res[io][nt][r]);
            *(us4*)(tl+p*C_+c0)=pk;
        }
    }
    __syncthreads();
    {
        bf16t* ob0=comb+(size_t)sb0*CP_;
        const unsigned short* t0=(const unsigned short*)LA[0];
        for(int j=t;j<1936;j+=512)
            *(bf16x8*)(ob0+j*8)=*(const bf16x8*)(t0+j*8);
        bf16t* ob1=comb+(size_t)(sb0+1)*CP_;
        const unsigned short* t1=(const unsigned short*)LA[1];
        for(int j=t;j<1936;j+=512)
            *(bf16x8*)(ob1+j*8)=*(const bf16x8*)(t1+j*8);
    }
}

// ================= fused GRU: zr conv + hhat conv + combine + LN =================
// LDS layout (bf16 elems): SB0=0, SB1=12176, SP0=24352, SP1=36528, SZ=48704 (stride 132)
// Z region: 121*132 = 15972 elems -> total 64676; lin sized 64704.
#define GSB0 0
#define GSB1 12176
#define GSP0 24352
#define GSP1 36528
#define GSZ  48704
#define SZSTR 132

#define LOADAZ(bidx, widx) { \
    _Pragma("unroll") \
    for(int mt=0;mt<2;mt++) abuf[bidx][mt]=*(const bf16x8*)(Wzr+(size_t)(widx)*(256*32)+mt*512+base_laneZ); }
#define LOADAH(bidx, widx) { \
    _Pragma("unroll") \
    for(int mt=0;mt<2;mt++) abuf[bidx][mt]=*(const bf16x8*)(Wh+(size_t)(widx)*(128*32)+mt*512+base_laneH); }
#define STEPZ8(lbase, bidx, doff) { \
    bf16x8 bb[8]; \
    _Pragma("unroll") \
    for(int nt=0;nt<8;nt++) bb[nt]=*(const bf16x8*)(lin+(lbase)+boffZ[nt]+(doff)); \
    __builtin_amdgcn_s_setprio(1); \
    _Pragma("unroll") \
    for(int mt=0;mt<2;mt++){ \
        _Pragma("unroll") \
        for(int nt=0;nt<8;nt++) \
            accZ[mt][nt]=__builtin_amdgcn_mfma_f32_16x16x32_bf16(abuf[bidx][mt],bb[nt],accZ[mt][nt],0,0,0); } \
    __builtin_amdgcn_s_setprio(0); }
#define STEPH4(lbase, bidx, doff) { \
    bf16x8 bb[4]; \
    _Pragma("unroll") \
    for(int nt=0;nt<4;nt++) bb[nt]=*(const bf16x8*)(lin+(lbase)+boffH[nt]+(doff)); \
    __builtin_amdgcn_s_setprio(1); \
    _Pragma("unroll") \
    for(int mt=0;mt<2;mt++){ \
        _Pragma("unroll") \
        for(int nt=0;nt<4;nt++) \
            accH[mt][nt]=__builtin_amdgcn_mfma_f32_16x16x32_bf16(abuf[bidx][mt],bb[nt],accH[mt][nt],0,0,0); } \
    __builtin_amdgcn_s_setprio(0); }
#define SLOADG(srcp) { \
    sreg[0]=*(const bf16x8*)((srcp)+(size_t)spA*C_+(t&7)*8); \
    if(sv1) sreg[1]=*(const bf16x8*)((srcp)+(size_t)spB*C_+(t&7)*8); }
#define SWRITEG(lbase) { \
    *(bf16x8*)(lin+(lbase)+spixA*72+(t&7)*8)=sreg[0]; \
    if(sv1) *(bf16x8*)(lin+(lbase)+spixB*72+(t&7)*8)=sreg[1]; }

__global__ __launch_bounds__(512) void gru_fused(
    bf16t* __restrict__ hTout, const bf16t* __restrict__ comb, const bf16t* __restrict__ hTb,
    const bf16t* __restrict__ Wzr, const float* __restrict__ bzr,
    const bf16t* __restrict__ Wh, const float* __restrict__ bh,
    const float* __restrict__ gamT, const float* __restrict__ betT,
    int last, void* __restrict__ fout, const int* __restrict__ flag)
{
    __shared__ bf16t lin[64704];
    __shared__ float red[16];
    int sb=blockIdx.x, t=threadIdx.x, lane=t&63, w=t>>6;
    int l15=lane&15, kg=lane>>4;
    // staging geometry
    bf16x8 sreg[2];
    bool sv1=((t+512)<968);
    int spA=t>>3, spB=(t+512)>>3;
    if(spB>120) spB=120;
    int spixA=(spA/11+1)*13+(spA%11)+1;
    int spixB=(spB/11+1)*13+(spB%11)+1;
    // ---------------- zr phase: wave = 32oc x 128p ----------------
    int boffZ[8]; bool pvZ[8];
    #pragma unroll
    for(int nt=0;nt<8;nt++){
        int p=nt*16+l15;
        pvZ[nt]=(p<P_); int pc=pvZ[nt]?p:(P_-1);
        boffZ[nt]=((pc/11)*13+(pc%11))*72+kg*8;
    }
    f32x4 accZ[2][8];
    #pragma unroll
    for(int i=0;i<2;i++){
        #pragma unroll
        for(int j=0;j<8;j++) accZ[i][j]=(f32x4){0.f,0.f,0.f,0.f};
    }
    int base_laneZ=(w*32+l15)*32+kg*8;
    bf16x8 abuf[4][2];
    LOADAZ(0,0); LOADAZ(1,1); LOADAZ(2,8); LOADAZ(3,9);
    SLOADG(comb+(size_t)sb*CP_);         // zr stage 0 = comb[0:64]
    {
        bf16x8 z;
        #pragma unroll
        for(int e=0;e<8;e++) z[e]=0;
        for(int i=t;i<1536;i+=512){
            int tile=i/384; int i2=i-tile*384;
            int bi=i2>>3, cc=(i2&7)*8;
            int pix;
            if(bi<13) pix=bi;
            else if(bi<26) pix=156+(bi-13);
            else { int j2=bi-26; pix=(1+(j2>>1))*13+((j2&1)?12:0); }
            *(bf16x8*)(lin+tile*12176+pix*72+cc)=z;
        }
    }
    SWRITEG(GSB0);
    __syncthreads();
    #pragma unroll
    for(int st=0; st<4; ++st){
        if(st<3){
            const bf16t* nsrc=((st+1)<2? comb:hTb)+(size_t)sb*CP_+((st+1)&1)*64;
            SLOADG(nsrc);
        }
        int lbase=(st&1)? GSB1:GSB0;
        #pragma unroll
        for(int k=0;k<18;k++){
            int s=st*18+k;
            int tap=k>>1, l=k&1;
            int doff=((tap/3)*13+(tap%3))*72+l*32;
            STEPZ8(lbase, s&3, doff);
            if(s<68){
                int s4=s+4, st4=s4/18, k4=s4-st4*18, tap4=k4>>1, l4=k4&1;
                LOADAZ(s&3, tap4*8+st4*2+l4);
            }
        }
        if(st<3){ SWRITEG(((st+1)&1)? GSB1:GSB0); }
        __syncthreads();
    }
    // zr epilogue -> LDS
    if(w<4){
        #pragma unroll
        for(int mt=0;mt<2;mt++){
            int oc=w*32+mt*16+kg*4;
            #pragma unroll
            for(int nt=0;nt<8;nt++){
                if(!pvZ[nt]) continue;
                int p=nt*16+l15;
                us4 pk;
                #pragma unroll
                for(int r=0;r<4;r++){ float a=accZ[mt][nt][r]+bzr[oc+r]; pk[r]=f2bu(1.f/(1.f+__expf(-a))); }
                *(us4*)(lin+GSZ+p*SZSTR+oc)=pk;
            }
        }
    }else{
        int icb=w-4;
        #pragma unroll
        for(int mt=0;mt<2;mt++){
            int ic=icb*32+mt*16+kg*4;
            int tb=(ic<64)? GSP0:GSP1;
            int icl=ic&63;
            #pragma unroll
            for(int nt=0;nt<8;nt++){
                if(!pvZ[nt]) continue;
                int p=nt*16+l15;
                int pixE=(p/11+1)*13+(p%11)+1;
                us4 hv=*(const us4*)(hTb+(size_t)sb*CP_+(size_t)p*C_+ic);
                us4 pk;
                #pragma unroll
                for(int r=0;r<4;r++){
                    float a=accZ[mt][nt][r]+bzr[128+ic+r];
                    float sg=1.f/(1.f+__expf(-a));
                    pk[r]=f2bu(sg*b2f(hv[r]));
                }
                *(us4*)(lin+tb+pixE*72+icl)=pk;
            }
        }
    }
    __syncthreads();
    // ---------------- hh phase: wave = 32oc x 64p; stage order [RH0,RH1,comb0,comb1] ----------------
    int ocrH=w>>1, pcrH=w&1;
    int boffH[4]; bool pvH[4];
    #pragma unroll
    for(int nt=0;nt<4;nt++){
        int p=pcrH*64+nt*16+l15;
        pvH[nt]=(p<P_); int pc=pvH[nt]?p:(P_-1);
        boffH[nt]=((pc/11)*13+(pc%11))*72+kg*8;
    }
    f32x4 accH[2][4];
    #pragma unroll
    for(int i=0;i<2;i++){
        #pragma unroll
        for(int j=0;j<4;j++) accH[i][j]=(f32x4){0.f,0.f,0.f,0.f};
    }
    int base_laneH=(ocrH*32+l15)*32+kg*8;
    LOADAH(0,4); LOADAH(1,5); LOADAH(2,12); LOADAH(3,13);
    SLOADG(comb+(size_t)sb*CP_);
    #pragma unroll
    for(int sidx=0; sidx<4; ++sidx){
        if(sidx==2){
            SWRITEG(GSB0);
            SLOADG(comb+(size_t)sb*CP_+64);
            __syncthreads();
        }
        if(sidx==3){
            SWRITEG(GSB1);
            __syncthreads();
        }
        int lbase=(sidx==0)?GSP0:(sidx==1)?GSP1:(sidx==2)?GSB0:GSB1;
        #pragma unroll
        for(int k=0;k<18;k++){
            int s=sidx*18+k;
            int tap=k>>1, l=k&1;
            int doff=((tap/3)*13+(tap%3))*72+l*32;
            STEPH4(lbase, s&3, doff);
            if(s<68){
                int s4=s+4, sidx4=s4/18, k4=s4-sidx4*18, tap4=k4>>1, l4=k4&1;
                int st4=(sidx4<2)?(2+sidx4):(sidx4-2);
                LOADAH(s&3, tap4*8+st4*2+l4);
            }
        }
    }
    __syncthreads();
    // combine -> NH at lin[0 .. 15488) as [p][128c]
    float ls=0.f, ls2=0.f;
    #pragma unroll
    for(int mt=0;mt<2;mt++){
        int oc=ocrH*32+mt*16+kg*4;
        #pragma unroll
        for(int nt=0;nt<4;nt++){
            if(!pvH[nt]) continue;
            int p=pcrH*64+nt*16+l15;
            us4 hv=*(const us4*)(hTb+(size_t)sb*CP_+(size_t)p*C_+oc);
            us4 zv=*(const us4*)(lin+GSZ+p*SZSTR+oc);
            us4 pk;
            #pragma unroll
            for(int r=0;r<4;r++){
                float a=accH[mt][nt][r]+bh[oc+r];
                float ht=tanhf(a);
                float z=b2f(zv[r]), h=b2f(hv[r]);
                unsigned short u=f2bu((1.f-z)*h+z*ht+h);
                pk[r]=u;
                float nr=b2f(u); ls+=nr; ls2+=nr*nr;
            }
            *(us4*)((unsigned short*)lin + p*C_+oc)=pk;
        }
    }
    #pragma unroll
    for(int o=32;o;o>>=1){ ls+=__shfl_xor(ls,o); ls2+=__shfl_xor(ls2,o); }
    if(lane==0){ red[w]=ls; red[8+w]=ls2; }
    __syncthreads();
    float Sx=0.f,Sx2=0.f;
    #pragma unroll
    for(int i=0;i<8;i++){ Sx+=red[i]; Sx2+=red[8+i]; }
    float mu=Sx*(1.f/(float)CP_);
    float var=Sx2*(1.f/(float)CP_)-mu*mu;
    float rstd=rsqrtf(var+1e-5f);
    const unsigned short* tl=(const unsigned short*)lin;
    if(!last){
        bf16t* ho=hTout+(size_t)sb*CP_;
        for(int j=t;j<1936;j+=512){
            int base=j*8;
            bf16x8 ovec;
            #pragma unroll
            for(int e=0;e<8;e++){
                float v=(b2f(tl[base+e])-mu)*rstd*gamT[base+e]+betT[base+e];
                ovec[e]=(short)f2bu(v);
            }
            *(bf16x8*)(ho+base)=ovec;
        }
    }else{
        int f=*flag;
        for(int j=t;j<CP_;j+=512){
            int c=j/P_, p=j-c*P_;
            int jj=p*C_+c;
            float v=(b2f(tl[jj])-mu)*rstd*gamT[jj]+betT[jj];
            size_t oi=(size_t)sb*CP_+j;
            if(f) ((float*)fout)[oi]=v;
            else  ((bf16t*)fout)[oi]=__float2bfloat16(v);
        }
    }
}

extern "C" void kernel_launch(void* const* d_in, const int* in_sizes, int n_in,
                              void* d_out, int out_size, void* d_ws, size_t ws_size,
                              hipStream_t stream) {
    (void)in_sizes; (void)n_in; (void)out_size;
    char* base=(char*)d_ws;
    size_t off=0;
    auto alloc=[&](size_t bytes){ void* p=base+off; off+=(bytes+255)&~(size_t)255; return p; };
    bf16t* b1=(bf16t*)alloc((size_t)NEl*2+8192);          // hT
    bf16t* b2=(bf16t*)alloc((size_t)NEl*2+8192);          // comb
    bf16t* wqT=(bf16t*)alloc(16384*2);
    bf16t* wkT=(bf16t*)alloc(16384*2);
    bf16t* wvT=(bf16t*)alloc(16384*2);
    bf16t* w2T=(bf16t*)alloc(16384*2);
    bf16t* wzrT=(bf16t*)alloc((size_t)589824*2);
    bf16t* whT =(bf16t*)alloc((size_t)294912*2);
    float* W2f=(float*)alloc(16384*4);
    float* b2l=(float*)alloc(128*4); float* b2r=(float*)alloc(128*4);
    float* bqf=(float*)alloc(128*4); float* bkf=(float*)alloc(128*4); float* bvf=(float*)alloc(128*4);
    float* bzrf=(float*)alloc(256*4); float* bhf=(float*)alloc(128*4);
    float* gamT=(float*)alloc(15488*4); float* betT=(float*)alloc(15488*4);
    float* wgTf=(float*)alloc(16384*4); float* bgf2=(float*)alloc(128*4);
    float* alphaf=(float*)alloc(4); float* weightf=(float*)alloc(4);
    int* flag=(int*)alloc(4);
    if(ws_size<off) return;  // ~70MB needed

    detect_kernel<<<1,64,0,stream>>>((const unsigned short*)d_in[0],flag);
    cvtT_kernel<<<SBn,256,0,stream>>>(b1,d_in[0],flag);
    prep_small<<<381,256,0,stream>>>(wqT,wkT,wvT,wgTf,gamT,betT,
        bqf,bkf,bvf,bzrf,bhf,bgf2,alphaf,weightf,
        d_in[1],d_in[3],d_in[5],d_in[12],d_in[18],d_in[19],
        d_in[2],d_in[4],d_in[6],d_in[15],d_in[17],d_in[13],
        d_in[7],d_in[11],flag);
    prep_msg_kernel<<<C_,C_,0,stream>>>(W2f,b2l,b2r,d_in[10],d_in[8],d_in[9],flag);
    prep_w1tf<<<64,256,0,stream>>>(w2T,W2f);
    prep_w3t<<<(256*2304+255)/256,256,0,stream>>>(wzrT,d_in[14],flag,256);
    prep_w3t<<<(128*2304+255)/256,256,0,stream>>>(whT,d_in[16],flag,128);

    for(int it=0; it<3; ++it){
        attn2<<<SBn/2,512,0,stream>>>(b2,b1,wqT,wkT,wvT,bqf,bkf,bvf,
                                      w2T,b2l,b2r,wgTf,bgf2,alphaf,weightf);
        gru_fused<<<SBn,512,0,stream>>>(b1,b2,b1,wzrT,bzrf,whT,bhf,gamT,betT,
                                        (it==2)?1:0,d_out,flag);
    }
}

// Round 23
// 1232.436 us; speedup vs baseline: 1.0233x; 1.0233x over previous
//
#include <hip/hip_runtime.h>
#include <hip/hip_bf16.h>

// GraphProcessor: S=16,B=64,C=128,H=W=11,P=121, 3 iterations.
// Round 23: prep_small consolidation kept; gru_fused restored to verified r21 form;
// separate finalT kernel restored (r22's fused-final perturbed codegen, -50us/dispatch).
#define S_   16
#define B_   64
#define SBn  1024
#define C_   128
#define P_   121
#define CP_  15488
#define LTS  17408   // 128*136
static const long NEl = 15859712L; // SBn*CP_

typedef __hip_bfloat16 bf16t;
typedef __attribute__((ext_vector_type(8))) short bf16x8;
typedef __attribute__((ext_vector_type(4))) float f32x4;
typedef __attribute__((ext_vector_type(4))) unsigned short us4;

__device__ __forceinline__ float ldb(const bf16t* p){ return __bfloat162float(*p); }
__device__ __forceinline__ float b2f(unsigned short u){ unsigned x=((unsigned)u)<<16; float f; __builtin_memcpy(&f,&x,4); return f; }
__device__ __forceinline__ unsigned short f2bu(float v){ __hip_bfloat16 b=__float2bfloat16(v); unsigned short u; __builtin_memcpy(&u,&b,2); return u; }
__device__ __forceinline__ float ldin(const void* s, long i, int f){
    return f ? ((const float*)s)[i] : b2f(((const unsigned short*)s)[i]);
}

// ---------- dtype detect ----------
__global__ void detect_kernel(const unsigned short* __restrict__ x, int* __restrict__ flag){
    if(blockIdx.x==0 && threadIdx.x==0){
        int crazy=0;
        for(int i=0;i<512;i++){
            unsigned e=(x[i]>>7)&0xFF;
            if(e!=0 && (e<64 || e>191)) crazy++;
        }
        *flag=(crazy>40)?1:0;
    }
}

__global__ __launch_bounds__(256) void cvtT_kernel(bf16t* __restrict__ hT, const void* __restrict__ x, const int* __restrict__ flag){
    __shared__ bf16t tl[CP_];
    int sb=blockIdx.x, t=threadIdx.x; int f=*flag;
    for(int i=t;i<CP_;i+=256)
        tl[i]=__float2bfloat16(ldin(x,(long)sb*CP_+i,f));
    __syncthreads();
    bf16t* ho=hT+(size_t)sb*CP_;
    for(int j=t;j<CP_;j+=256){
        int p=j>>7, c=j&127;
        ho[j]=tl[c*P_+p];
    }
}

// ---------- merged small-prep: q/k/v weight tiles, wgT, gamT/betT, all biases+scalars ----------
__global__ __launch_bounds__(256) void prep_small(
    bf16t* __restrict__ wqT, bf16t* __restrict__ wkT, bf16t* __restrict__ wvT, float* __restrict__ wgT,
    float* __restrict__ gamT, float* __restrict__ betT,
    float* __restrict__ bqf, float* __restrict__ bkf, float* __restrict__ bvf,
    float* __restrict__ bzrf, float* __restrict__ bhf, float* __restrict__ bgf2,
    float* __restrict__ alphaf, float* __restrict__ weightf,
    const void* dwq, const void* dwk, const void* dwv, const void* dwg,
    const void* dgam, const void* dbet,
    const void* dbq, const void* dbk, const void* dbv, const void* dbzr, const void* dbh, const void* dbg,
    const void* dal, const void* dwt,
    const int* __restrict__ flag)
{
    int idx=blockIdx.x*256+threadIdx.x;
    int f=*flag;
    if(idx<16384){
        int r=idx&31, oc=(idx>>5)&127, icb=idx>>12;
        wqT[idx]=__float2bfloat16(ldin(dwq,(long)oc*C_+icb*32+r,f));
    }else if(idx<32768){
        int l=idx-16384; int r=l&31, oc=(l>>5)&127, icb=l>>12;
        wkT[l]=__float2bfloat16(ldin(dwk,(long)oc*C_+icb*32+r,f));
    }else if(idx<49152){
        int l=idx-32768; int r=l&31, oc=(l>>5)&127, icb=l>>12;
        wvT[l]=__float2bfloat16(ldin(dwv,(long)oc*C_+icb*32+r,f));
    }else if(idx<65536){
        int l=idx-49152; int k=l>>7, c=l&127;
        wgT[l]=ldin(dwg,(long)c*C_+k,f);
    }else if(idx<81024){
        int l=idx-65536; int c=l/P_, p=l-c*P_;
        gamT[p*C_+c]=ldin(dgam,l,f);
    }else if(idx<96512){
        int l=idx-81024; int c=l/P_, p=l-c*P_;
        betT[p*C_+c]=ldin(dbet,l,f);
    }else if(idx<97442){
        int l=idx-96512;
        if(l<128)       bqf[l]      =ldin(dbq,l,f);
        else if(l<256)  bkf[l-128]  =ldin(dbk,l-128,f);
        else if(l<384)  bvf[l-256]  =ldin(dbv,l-256,f);
        else if(l<640)  bzrf[l-384] =ldin(dbzr,l-384,f);
        else if(l<768)  bhf[l-640]  =ldin(dbh,l-640,f);
        else if(l<896)  bgf2[l-768] =ldin(dbg,l-768,f);
        else if(l==896) alphaf[0]   =ldin(dal,0,f);
        else if(l==897) weightf[0]  =ldin(dwt,0,f);
    }
}

__global__ __launch_bounds__(128) void prep_msg_kernel(float* __restrict__ W2, float* __restrict__ b2l, float* __restrict__ b2r,
        const void* __restrict__ wlin, const void* __restrict__ wmsg, const void* __restrict__ bmsg, const int* __restrict__ flag){
    int d=blockIdx.x, c=threadIdx.x; int f=*flag;
    float acc=0.f;
    for(int o2=0;o2<C_;o2++) acc += ldin(wlin,(long)d*C_+o2,f)*ldin(wmsg,(long)o2*(C_+1)+c,f);
    W2[d*C_+c]=acc;
    if(c<2){
        float e=(c==0)?1.f:-1.f; float a=0.f;
        for(int o2=0;o2<C_;o2++) a += ldin(wlin,(long)d*C_+o2,f)*(ldin(bmsg,o2,f)+e*ldin(wmsg,(long)o2*(C_+1)+C_,f));
        if(c==0) b2l[d]=a; else b2r[d]=a;
    }
}

__global__ void prep_w1tf(bf16t* __restrict__ dst, const float* __restrict__ src){
    int idx=blockIdx.x*blockDim.x+threadIdx.x;
    if(idx>=16384) return;
    int r=idx&31, oc=(idx>>5)&127, icb=idx>>12;
    dst[idx]=__float2bfloat16(src[(long)oc*C_+icb*32+r]);
}

__global__ void prep_w3t(bf16t* __restrict__ dst, const void* __restrict__ src, const int* __restrict__ flag, int OC){
    int idx=blockIdx.x*blockDim.x+threadIdx.x;
    int tot=OC*2304;
    if(idx>=tot) return;
    int r=idx&31; int rest=idx>>5; int oc=rest%OC; int g2=rest/OC; int icb=g2&7, tap=g2>>3;
    float v=ldin(src,((long)(oc*256+icb*32+r))*9+tap,*flag);
    dst[idx]=__float2bfloat16(v);
}

// ---------- 128x128x128 GEMM tile, 8 waves (2 ocr x 4 pcr), B from registers ----------
__device__ __forceinline__ void gemm24r(f32x4 (&acc)[4][2],
    const bf16t* __restrict__ Wt, const bf16x8 (&hreg)[4][2],
    int ocr,int l15,int kg)
{
    #pragma unroll
    for(int i=0;i<4;i++){
        #pragma unroll
        for(int j=0;j<2;j++) acc[i][j]=(f32x4){0.f,0.f,0.f,0.f};
    }
    #pragma unroll
    for(int kc=0;kc<4;kc++){
        bf16x8 a[4];
        #pragma unroll
        for(int mt=0;mt<4;mt++) a[mt]=*(const bf16x8*)(Wt+((size_t)(kc*C_+ocr*64+mt*16+l15))*32+kg*8);
        #pragma unroll
        for(int mt=0;mt<4;mt++){
            #pragma unroll
            for(int nt=0;nt<2;nt++)
                acc[mt][nt]=__builtin_amdgcn_mfma_f32_16x16x32_bf16(a[mt],hreg[kc][nt],acc[mt][nt],0,0,0);
        }
    }
}

// ---------- dual message phase ----------
__device__ __forceinline__ void msg_phase2(
    f32x4 (&res)[2][8], const bf16t* __restrict__ hT, int sb0, int shift,
    const bf16t* __restrict__ W2T, const float* __restrict__ b2e,
    const float* __restrict__ wgT, const float* __restrict__ bgf, float w1m,
    const bf16x8 (&areg)[2][4],
    bf16t (*LA)[LTS], bf16t (*LB)[LTS], float (*fl)[256],
    int t,int w,int l15,int kg,int ocr,int pcr)
{
    __syncthreads();
    int m0=w*16;
    #pragma unroll
    for(int io=0;io<2;io++){
        const bf16t* hsp=hT+(size_t)(sb0+io+shift)*CP_;
        bf16x8 hregS[4][2];
        #pragma unroll
        for(int kc=0;kc<4;kc++){
            #pragma unroll
            for(int nt=0;nt<2;nt++)
                hregS[kc][nt]=*(const bf16x8*)(hsp+(size_t)(pcr*32+nt*16+l15)*C_+kc*32+kg*8);
        }
        f32x4 acc[4][2];
        gemm24r(acc,W2T,hregS,ocr,l15,kg);
        #pragma unroll
        for(int mt=0;mt<4;mt++){
            int oc0=ocr*64+mt*16+kg*4;
            #pragma unroll
            for(int nt=0;nt<2;nt++){
                int p=pcr*32+nt*16+l15;
                us4 pk;
                #pragma unroll
                for(int r=0;r<4;r++){
                    float v=acc[mt][nt][r]+b2e[oc0+r];
                    pk[r]=f2bu(v);
                    LB[io][(oc0+r)*136+p]=__float2bfloat16(p<P_? v : 0.f);
                }
                *(us4*)(LA[io]+p*136+oc0)=pk;
            }
        }
    }
    __syncthreads();
    f32x4 s[2][8];
    #pragma unroll
    for(int io=0;io<2;io++){
        #pragma unroll
        for(int nt=0;nt<8;nt++) s[io][nt]=(f32x4){0.f,0.f,0.f,0.f};
        #pragma unroll
        for(int kc=0;kc<4;kc++){
            #pragma unroll
            for(int nt=0;nt<8;nt++){
                bf16x8 b=*(const bf16x8*)(LA[io]+(size_t)(nt*16+l15)*136+kc*32+kg*8);
                s[io][nt]=__builtin_amdgcn_mfma_f32_16x16x32_bf16(areg[io][kc],b,s[io][nt],0,0,0);
            }
        }
        if(l15>=9){
            #pragma unroll
            for(int r=0;r<4;r++) s[io][7][r]=-3.0e38f;
        }
        #pragma unroll
        for(int r=0;r<4;r++){
            float mx=s[io][0][r];
            #pragma unroll
            for(int nt=1;nt<8;nt++) mx=fmaxf(mx,s[io][nt][r]);
            #pragma unroll
            for(int o=1;o<16;o<<=1) mx=fmaxf(mx,__shfl_xor(mx,o));
            float sm=0.f;
            #pragma unroll
            for(int nt=0;nt<8;nt++){ float e=__expf(s[io][nt][r]-mx); s[io][nt][r]=e; sm+=e; }
            #pragma unroll
            for(int o=1;o<16;o<<=1) sm+=__shfl_xor(sm,o);
            float rs=1.f/sm;
            #pragma unroll
            for(int nt=0;nt<8;nt++) s[io][nt][r]*=rs;
        }
    }
    __syncthreads();
    #pragma unroll
    for(int io=0;io<2;io++){
        #pragma unroll
        for(int r=0;r<4;r++){
            int pr=m0+kg*4+r;
            #pragma unroll
            for(int nt=0;nt<8;nt++) LA[io][pr*136+nt*16+l15]=__float2bfloat16(s[io][nt][r]);
        }
    }
    __syncthreads();
    f32x4 o[2][8];
    #pragma unroll
    for(int io=0;io<2;io++){
        #pragma unroll
        for(int nt=0;nt<8;nt++) o[io][nt]=(f32x4){0.f,0.f,0.f,0.f};
        #pragma unroll
        for(int jc=0;jc<4;jc++){
            bf16x8 a=*(const bf16x8*)(LB[io]+(size_t)(m0+l15)*136+jc*32+kg*8);
            #pragma unroll
            for(int nt=0;nt<8;nt++){
                bf16x8 b=*(const bf16x8*)(LA[io]+(size_t)(nt*16+l15)*136+jc*32+kg*8);
                o[io][nt]=__builtin_amdgcn_mfma_f32_16x16x32_bf16(a,b,o[io][nt],0,0,0);
            }
        }
    }
    int c0=m0+kg*4;
    #pragma unroll
    for(int io=0;io<2;io++){
        #pragma unroll
        for(int r=0;r<4;r++){
            float sm=0.f;
            #pragma unroll
            for(int nt=0;nt<8;nt++){ float v=o[io][nt][r]; if(nt==7&&l15>8) v=0.f; sm+=v; }
            sm+=__shfl_xor(sm,1); sm+=__shfl_xor(sm,2); sm+=__shfl_xor(sm,4); sm+=__shfl_xor(sm,8);
            if(l15==0) fl[io][c0+r]=sm*(1.f/121.f);
        }
    }
    __syncthreads();
    if(t<256){
        int which=t>>7, c=t&127;
        float a=bgf[c];
        #pragma unroll 8
        for(int k=0;k<C_;k++) a+=wgT[k*C_+c]*fl[which][k];
        fl[which][C_+c]=1.f/(1.f+__expf(-a));
    }
    __syncthreads();
    #pragma unroll
    for(int io=0;io<2;io++){
        float gg[4];
        #pragma unroll
        for(int r=0;r<4;r++) gg[r]=fl[io][C_+c0+r];
        #pragma unroll
        for(int nt=0;nt<8;nt++){
            #pragma unroll
            for(int r=0;r<4;r++) res[io][nt][r]+=w1m*o[io][nt][r]*gg[r];
        }
    }
}

// ---------- fused intra + msgs for a PAIR of sb, 512 threads ----------
__global__ __launch_bounds__(512) void attn2(
    bf16t* __restrict__ comb, const bf16t* __restrict__ hT,
    const bf16t* __restrict__ WqT, const bf16t* __restrict__ WkT, const bf16t* __restrict__ WvT,
    const float* __restrict__ bq, const float* __restrict__ bk, const float* __restrict__ bv,
    const bf16t* __restrict__ W2T, const float* __restrict__ b2l, const float* __restrict__ b2r,
    const float* __restrict__ wgT, const float* __restrict__ bgf,
    const float* __restrict__ alphap, const float* __restrict__ wp)
{
    __shared__ bf16t LA[2][LTS];
    __shared__ bf16t LB[2][LTS];
    __shared__ float fl[2][256];
    int sb0=(int)blockIdx.x*2, t=threadIdx.x, lane=t&63, w=t>>6;
    int l15=lane&15, kg=lane>>4;
    int ocr=w>>2, pcr=w&3;
    int m0=w*16;
    const bf16t* hp0=hT+(size_t)sb0*CP_;
    const bf16t* hp1=hp0+CP_;
    bf16x8 hreg[2][4][2];
    bf16x8 areg[2][4];
    #pragma unroll
    for(int kc=0;kc<4;kc++){
        #pragma unroll
        for(int nt=0;nt<2;nt++){
            hreg[0][kc][nt]=*(const bf16x8*)(hp0+(size_t)(pcr*32+nt*16+l15)*C_+kc*32+kg*8);
            hreg[1][kc][nt]=*(const bf16x8*)(hp1+(size_t)(pcr*32+nt*16+l15)*C_+kc*32+kg*8);
        }
        areg[0][kc]=*(const bf16x8*)(hp0+(size_t)(m0+l15)*C_+kc*32+kg*8);
        areg[1][kc]=*(const bf16x8*)(hp1+(size_t)(m0+l15)*C_+kc*32+kg*8);
    }
    #pragma unroll
    for(int io=0;io<2;io++){
        f32x4 acc[4][2];
        gemm24r(acc,WqT,hreg[io],ocr,l15,kg);
        #pragma unroll
        for(int mt=0;mt<4;mt++){
            int oc0=ocr*64+mt*16+kg*4;
            #pragma unroll
            for(int nt=0;nt<2;nt++){
                int p=pcr*32+nt*16+l15;
                us4 pk;
                #pragma unroll
                for(int r=0;r<4;r++) pk[r]=f2bu(acc[mt][nt][r]+bq[oc0+r]);
                *(us4*)(LA[io]+p*136+oc0)=pk;
            }
        }
        gemm24r(acc,WkT,hreg[io],ocr,l15,kg);
        #pragma unroll
        for(int mt=0;mt<4;mt++){
            int oc0=ocr*64+mt*16+kg*4;
            #pragma unroll
            for(int nt=0;nt<2;nt++){
                int p=pcr*32+nt*16+l15;
                us4 pk;
                #pragma unroll
                for(int r=0;r<4;r++) pk[r]=f2bu(acc[mt][nt][r]+bk[oc0+r]);
                *(us4*)(LB[io]+p*136+oc0)=pk;
            }
        }
    }
    __syncthreads();
    const float scale=0.08838834764831845f;
    f32x4 s[2][8];
    #pragma unroll
    for(int io=0;io<2;io++){
        #pragma unroll
        for(int nt=0;nt<8;nt++) s[io][nt]=(f32x4){0.f,0.f,0.f,0.f};
        #pragma unroll
        for(int kc=0;kc<4;kc++){
            bf16x8 a=*(const bf16x8*)(LA[io]+(size_t)(m0+l15)*136+kc*32+kg*8);
            #pragma unroll
            for(int nt=0;nt<8;nt++){
                bf16x8 b=*(const bf16x8*)(LB[io]+(size_t)(nt*16+l15)*136+kc*32+kg*8);
                s[io][nt]=__builtin_amdgcn_mfma_f32_16x16x32_bf16(a,b,s[io][nt],0,0,0);
            }
        }
        #pragma unroll
        for(int nt=0;nt<8;nt++){
            #pragma unroll
            for(int r=0;r<4;r++) s[io][nt][r]*=scale;
        }
        if(l15>=9){
            #pragma unroll
            for(int r=0;r<4;r++) s[io][7][r]=-3.0e38f;
        }
        #pragma unroll
        for(int r=0;r<4;r++){
            float mx=s[io][0][r];
            #pragma unroll
            for(int nt=1;nt<8;nt++) mx=fmaxf(mx,s[io][nt][r]);
            #pragma unroll
            for(int o=1;o<16;o<<=1) mx=fmaxf(mx,__shfl_xor(mx,o));
            float sm=0.f;
            #pragma unroll
            for(int nt=0;nt<8;nt++){ float e=__expf(s[io][nt][r]-mx); s[io][nt][r]=e; sm+=e; }
            #pragma unroll
            for(int o=1;o<16;o<<=1) sm+=__shfl_xor(sm,o);
            float rs=1.f/sm;
            #pragma unroll
            for(int nt=0;nt<8;nt++) s[io][nt][r]*=rs;
        }
    }
    __syncthreads();
    #pragma unroll
    for(int io=0;io<2;io++){
        f32x4 acc[4][2];
        gemm24r(acc,WvT,hreg[io],ocr,l15,kg);
        #pragma unroll
        for(int mt=0;mt<4;mt++){
            int oc0=ocr*64+mt*16+kg*4;
            #pragma unroll
            for(int nt=0;nt<2;nt++){
                int p=pcr*32+nt*16+l15;
                #pragma unroll
                for(int r=0;r<4;r++)
                    LA[io][(oc0+r)*136+p]=__float2bfloat16(p<P_? acc[mt][nt][r]+bv[oc0+r] : 0.f);
            }
        }
        #pragma unroll
        for(int r=0;r<4;r++){
            int pr=m0+kg*4+r;
            #pragma unroll
            for(int nt=0;nt<8;nt++) LB[io][pr*136+nt*16+l15]=__float2bfloat16(s[io][nt][r]);
        }
    }
    __syncthreads();
    float al=*alphap, wv=*wp, w1m=1.f-wv;
    int c0=m0+kg*4;
    f32x4 res[2][8];
    #pragma unroll
    for(int io=0;io<2;io++){
        #pragma unroll
        for(int nt=0;nt<8;nt++) res[io][nt]=(f32x4){0.f,0.f,0.f,0.f};
        #pragma unroll
        for(int jc=0;jc<4;jc++){
            bf16x8 a=*(const bf16x8*)(LA[io]+(size_t)(m0+l15)*136+jc*32+kg*8);
            #pragma unroll
            for(int nt=0;nt<8;nt++){
                bf16x8 b=*(const bf16x8*)(LB[io]+(size_t)(nt*16+l15)*136+jc*32+kg*8);
                res[io][nt]=__builtin_amdgcn_mfma_f32_16x16x32_bf16(a,b,res[io][nt],0,0,0);
            }
        }
        const bf16t* hp=(io==0)?hp0:hp1;
        #pragma unroll
        for(int nt=0;nt<8;nt++){
            int p=nt*16+l15;
            int pc=(p<P_)?p:(P_-1);
            us4 hv=*(const us4*)(hp+(size_t)pc*C_+c0);
            #pragma unroll
            for(int r=0;r<4;r++) res[io][nt][r]=wv*(al*res[io][nt][r]+b2f(hv[r]));
        }
    }
    if(sb0>=B_)
        msg_phase2(res,hT,sb0,-B_,W2T,b2l,wgT,bgf,w1m,areg,LA,LB,fl,t,w,l15,kg,ocr,pcr);
    if(sb0<SBn-B_)
        msg_phase2(res,hT,sb0, B_,W2T,b2r,wgT,bgf,w1m,areg,LA,LB,fl,t,w,l15,kg,ocr,pcr);
    __syncthreads();
    #pragma unroll
    for(int io=0;io<2;io++){
        unsigned short* tl=(unsigned short*)LA[io];
        #pragma unroll
        for(int nt=0;nt<8;nt++){
            int p=nt*16+l15;
            if(p>=P_) continue;
            us4 pk;
            #pragma unroll
            for(int r=0;r<4;r++) pk[r]=f2bu(res[io][nt][r]);
            *(us4*)(tl+p*C_+c0)=pk;
        }
    }
    __syncthreads();
    {
        bf16t* ob0=comb+(size_t)sb0*CP_;
        const unsigned short* t0=(const unsigned short*)LA[0];
        for(int j=t;j<1936;j+=512)
            *(bf16x8*)(ob0+j*8)=*(const bf16x8*)(t0+j*8);
        bf16t* ob1=comb+(size_t)(sb0+1)*CP_;
        const unsigned short* t1=(const unsigned short*)LA[1];
        for(int j=t;j<1936;j+=512)
            *(bf16x8*)(ob1+j*8)=*(const bf16x8*)(t1+j*8);
    }
}

// ================= fused GRU: zr conv + hhat conv + combine + LN (r21 form) =================
#define GSB0 0
#define GSB1 12176
#define GSP0 24352
#define GSP1 36528
#define GSZ  48704
#define SZSTR 132

#define LOADAZ(bidx, widx) { \
    _Pragma("unroll") \
    for(int mt=0;mt<2;mt++) abuf[bidx][mt]=*(const bf16x8*)(Wzr+(size_t)(widx)*(256*32)+mt*512+base_laneZ); }
#define LOADAH(bidx, widx) { \
    _Pragma("unroll") \
    for(int mt=0;mt<2;mt++) abuf[bidx][mt]=*(const bf16x8*)(Wh+(size_t)(widx)*(128*32)+mt*512+base_laneH); }
#define STEPZ8(lbase, bidx, doff) { \
    bf16x8 bb[8]; \
    _Pragma("unroll") \
    for(int nt=0;nt<8;nt++) bb[nt]=*(const bf16x8*)(lin+(lbase)+boffZ[nt]+(doff)); \
    __builtin_amdgcn_s_setprio(1); \
    _Pragma("unroll") \
    for(int mt=0;mt<2;mt++){ \
        _Pragma("unroll") \
        for(int nt=0;nt<8;nt++) \
            accZ[mt][nt]=__builtin_amdgcn_mfma_f32_16x16x32_bf16(abuf[bidx][mt],bb[nt],accZ[mt][nt],0,0,0); } \
    __builtin_amdgcn_s_setprio(0); }
#define STEPH4(lbase, bidx, doff) { \
    bf16x8 bb[4]; \
    _Pragma("unroll") \
    for(int nt=0;nt<4;nt++) bb[nt]=*(const bf16x8*)(lin+(lbase)+boffH[nt]+(doff)); \
    __builtin_amdgcn_s_setprio(1); \
    _Pragma("unroll") \
    for(int mt=0;mt<2;mt++){ \
        _Pragma("unroll") \
        for(int nt=0;nt<4;nt++) \
            accH[mt][nt]=__builtin_amdgcn_mfma_f32_16x16x32_bf16(abuf[bidx][mt],bb[nt],accH[mt][nt],0,0,0); } \
    __builtin_amdgcn_s_setprio(0); }
#define SLOADG(srcp) { \
    sreg[0]=*(const bf16x8*)((srcp)+(size_t)spA*C_+(t&7)*8); \
    if(sv1) sreg[1]=*(const bf16x8*)((srcp)+(size_t)spB*C_+(t&7)*8); }
#define SWRITEG(lbase) { \
    *(bf16x8*)(lin+(lbase)+spixA*72+(t&7)*8)=sreg[0]; \
    if(sv1) *(bf16x8*)(lin+(lbase)+spixB*72+(t&7)*8)=sreg[1]; }

__global__ __launch_bounds__(512) void gru_fused(
    bf16t* __restrict__ hTout, const bf16t* __restrict__ comb, const bf16t* __restrict__ hTb,
    const bf16t* __restrict__ Wzr, const float* __restrict__ bzr,
    const bf16t* __restrict__ Wh, const float* __restrict__ bh,
    const float* __restrict__ gamT, const float* __restrict__ betT)
{
    __shared__ bf16t lin[64704];
    __shared__ float red[16];
    int sb=blockIdx.x, t=threadIdx.x, lane=t&63, w=t>>6;
    int l15=lane&15, kg=lane>>4;
    bf16x8 sreg[2];
    bool sv1=((t+512)<968);
    int spA=t>>3, spB=(t+512)>>3;
    if(spB>120) spB=120;
    int spixA=(spA/11+1)*13+(spA%11)+1;
    int spixB=(spB/11+1)*13+(spB%11)+1;
    int boffZ[8]; bool pvZ[8];
    #pragma unroll
    for(int nt=0;nt<8;nt++){
        int p=nt*16+l15;
        pvZ[nt]=(p<P_); int pc=pvZ[nt]?p:(P_-1);
        boffZ[nt]=((pc/11)*13+(pc%11))*72+kg*8;
    }
    f32x4 accZ[2][8];
    #pragma unroll
    for(int i=0;i<2;i++){
        #pragma unroll
        for(int j=0;j<8;j++) accZ[i][j]=(f32x4){0.f,0.f,0.f,0.f};
    }
    int base_laneZ=(w*32+l15)*32+kg*8;
    bf16x8 abuf[4][2];
    LOADAZ(0,0); LOADAZ(1,1); LOADAZ(2,8); LOADAZ(3,9);
    SLOADG(comb+(size_t)sb*CP_);
    {
        bf16x8 z;
        #pragma unroll
        for(int e=0;e<8;e++) z[e]=0;
        for(int i=t;i<1536;i+=512){
            int tile=i/384; int i2=i-tile*384;
            int bi=i2>>3, cc=(i2&7)*8;
            int pix;
            if(bi<13) pix=bi;
            else if(bi<26) pix=156+(bi-13);
            else { int j2=bi-26; pix=(1+(j2>>1))*13+((j2&1)?12:0); }
            *(bf16x8*)(lin+tile*12176+pix*72+cc)=z;
        }
    }
    SWRITEG(GSB0);
    __syncthreads();
    #pragma unroll
    for(int st=0; st<4; ++st){
        if(st<3){
            const bf16t* nsrc=((st+1)<2? comb:hTb)+(size_t)sb*CP_+((st+1)&1)*64;
            SLOADG(nsrc);
        }
        int lbase=(st&1)? GSB1:GSB0;
        #pragma unroll
        for(int k=0;k<18;k++){
            int s=st*18+k;
            int tap=k>>1, l=k&1;
            int doff=((tap/3)*13+(tap%3))*72+l*32;
            STEPZ8(lbase, s&3, doff);
            if(s<68){
                int s4=s+4, st4=s4/18, k4=s4-st4*18, tap4=k4>>1, l4=k4&1;
                LOADAZ(s&3, tap4*8+st4*2+l4);
            }
        }
        if(st<3){ SWRITEG(((st+1)&1)? GSB1:GSB0); }
        __syncthreads();
    }
    if(w<4){
        #pragma unroll
        for(int mt=0;mt<2;mt++){
            int oc=w*32+mt*16+kg*4;
            #pragma unroll
            for(int nt=0;nt<8;nt++){
                if(!pvZ[nt]) continue;
                int p=nt*16+l15;
                us4 pk;
                #pragma unroll
                for(int r=0;r<4;r++){ float a=accZ[mt][nt][r]+bzr[oc+r]; pk[r]=f2bu(1.f/(1.f+__expf(-a))); }
                *(us4*)(lin+GSZ+p*SZSTR+oc)=pk;
            }
        }
    }else{
        int icb=w-4;
        #pragma unroll
        for(int mt=0;mt<2;mt++){
            int ic=icb*32+mt*16+kg*4;
            int tb=(ic<64)? GSP0:GSP1;
            int icl=ic&63;
            #pragma unroll
            for(int nt=0;nt<8;nt++){
                if(!pvZ[nt]) continue;
                int p=nt*16+l15;
                int pixE=(p/11+1)*13+(p%11)+1;
                us4 hv=*(const us4*)(hTb+(size_t)sb*CP_+(size_t)p*C_+ic);
                us4 pk;
                #pragma unroll
                for(int r=0;r<4;r++){
                    float a=accZ[mt][nt][r]+bzr[128+ic+r];
                    float sg=1.f/(1.f+__expf(-a));
                    pk[r]=f2bu(sg*b2f(hv[r]));
                }
                *(us4*)(lin+tb+pixE*72+icl)=pk;
            }
        }
    }
    __syncthreads();
    int ocrH=w>>1, pcrH=w&1;
    int boffH[4]; bool pvH[4];
    #pragma unroll
    for(int nt=0;nt<4;nt++){
        int p=pcrH*64+nt*16+l15;
        pvH[nt]=(p<P_); int pc=pvH[nt]?p:(P_-1);
        boffH[nt]=((pc/11)*13+(pc%11))*72+kg*8;
    }
    f32x4 accH[2][4];
    #pragma unroll
    for(int i=0;i<2;i++){
        #pragma unroll
        for(int j=0;j<4;j++) accH[i][j]=(f32x4){0.f,0.f,0.f,0.f};
    }
    int base_laneH=(ocrH*32+l15)*32+kg*8;
    LOADAH(0,4); LOADAH(1,5); LOADAH(2,12); LOADAH(3,13);
    SLOADG(comb+(size_t)sb*CP_);
    #pragma unroll
    for(int sidx=0; sidx<4; ++sidx){
        if(sidx==2){
            SWRITEG(GSB0);
            SLOADG(comb+(size_t)sb*CP_+64);
            __syncthreads();
        }
        if(sidx==3){
            SWRITEG(GSB1);
            __syncthreads();
        }
        int lbase=(sidx==0)?GSP0:(sidx==1)?GSP1:(sidx==2)?GSB0:GSB1;
        #pragma unroll
        for(int k=0;k<18;k++){
            int s=sidx*18+k;
            int tap=k>>1, l=k&1;
            int doff=((tap/3)*13+(tap%3))*72+l*32;
            STEPH4(lbase, s&3, doff);
            if(s<68){
                int s4=s+4, sidx4=s4/18, k4=s4-sidx4*18, tap4=k4>>1, l4=k4&1;
                int st4=(sidx4<2)?(2+sidx4):(sidx4-2);
                LOADAH(s&3, tap4*8+st4*2+l4);
            }
        }
    }
    __syncthreads();
    float ls=0.f, ls2=0.f;
    #pragma unroll
    for(int mt=0;mt<2;mt++){
        int oc=ocrH*32+mt*16+kg*4;
        #pragma unroll
        for(int nt=0;nt<4;nt++){
            if(!pvH[nt]) continue;
            int p=pcrH*64+nt*16+l15;
            us4 hv=*(const us4*)(hTb+(size_t)sb*CP_+(size_t)p*C_+oc);
            us4 zv=*(const us4*)(lin+GSZ+p*SZSTR+oc);
            us4 pk;
            #pragma unroll
            for(int r=0;r<4;r++){
                float a=accH[mt][nt][r]+bh[oc+r];
                float ht=tanhf(a);
                float z=b2f(zv[r]), h=b2f(hv[r]);
                unsigned short u=f2bu((1.f-z)*h+z*ht+h);
                pk[r]=u;
                float nr=b2f(u); ls+=nr; ls2+=nr*nr;
            }
            *(us4*)((unsigned short*)lin + p*C_+oc)=pk;
        }
    }
    #pragma unroll
    for(int o=32;o;o>>=1){ ls+=__shfl_xor(ls,o); ls2+=__shfl_xor(ls2,o); }
    if(lane==0){ red[w]=ls; red[8+w]=ls2; }
    __syncthreads();
    float Sx=0.f,Sx2=0.f;
    #pragma unroll
    for(int i=0;i<8;i++){ Sx+=red[i]; Sx2+=red[8+i]; }
    float mu=Sx*(1.f/(float)CP_);
    float var=Sx2*(1.f/(float)CP_)-mu*mu;
    float rstd=rsqrtf(var+1e-5f);
    bf16t* ho=hTout+(size_t)sb*CP_;
    const unsigned short* tl=(const unsigned short*)lin;
    for(int j=t;j<1936;j+=512){
        int base=j*8;
        bf16x8 ovec;
        #pragma unroll
        for(int e=0;e<8;e++){
            float v=(b2f(tl[base+e])-mu)*rstd*gamT[base+e]+betT[base+e];
            ovec[e]=(short)f2bu(v);
        }
        *(bf16x8*)(ho+base)=ovec;
    }
}

// ---------- final: hT [p][c] -> natural [c][p] output ----------
__global__ __launch_bounds__(256) void finalT_kernel(void* __restrict__ fout, const bf16t* __restrict__ hT, const int* __restrict__ flag){
    __shared__ bf16t tl[CP_];
    int sb=blockIdx.x, t=threadIdx.x, f=*flag;
    for(int i=t;i<CP_;i+=256) tl[i]=hT[(size_t)sb*CP_+i];
    __syncthreads();
    for(int i=t;i<CP_;i+=256){
        int c=i/P_, p=i-c*P_;
        float v=ldb(tl+p*C_+c);
        size_t oi=(size_t)sb*CP_+i;
        if(f) ((float*)fout)[oi]=v;
        else  ((bf16t*)fout)[oi]=__float2bfloat16(v);
    }
}

extern "C" void kernel_launch(void* const* d_in, const int* in_sizes, int n_in,
                              void* d_out, int out_size, void* d_ws, size_t ws_size,
                              hipStream_t stream) {
    (void)in_sizes; (void)n_in; (void)out_size;
    char* base=(char*)d_ws;
    size_t off=0;
    auto alloc=[&](size_t bytes){ void* p=base+off; off+=(bytes+255)&~(size_t)255; return p; };
    bf16t* b1=(bf16t*)alloc((size_t)NEl*2+8192);          // hT
    bf16t* b2=(bf16t*)alloc((size_t)NEl*2+8192);          // comb
    bf16t* wqT=(bf16t*)alloc(16384*2);
    bf16t* wkT=(bf16t*)alloc(16384*2);
    bf16t* wvT=(bf16t*)alloc(16384*2);
    bf16t* w2T=(bf16t*)alloc(16384*2);
    bf16t* wzrT=(bf16t*)alloc((size_t)589824*2);
    bf16t* whT =(bf16t*)alloc((size_t)294912*2);
    float* W2f=(float*)alloc(16384*4);
    float* b2l=(float*)alloc(128*4); float* b2r=(float*)alloc(128*4);
    float* bqf=(float*)alloc(128*4); float* bkf=(float*)alloc(128*4); float* bvf=(float*)alloc(128*4);
    float* bzrf=(float*)alloc(256*4); float* bhf=(float*)alloc(128*4);
    float* gamT=(float*)alloc(15488*4); float* betT=(float*)alloc(15488*4);
    float* wgTf=(float*)alloc(16384*4); float* bgf2=(float*)alloc(128*4);
    float* alphaf=(float*)alloc(4); float* weightf=(float*)alloc(4);
    int* flag=(int*)alloc(4);
    if(ws_size<off) return;  // ~70MB needed

    detect_kernel<<<1,64,0,stream>>>((const unsigned short*)d_in[0],flag);
    cvtT_kernel<<<SBn,256,0,stream>>>(b1,d_in[0],flag);
    prep_small<<<381,256,0,stream>>>(wqT,wkT,wvT,wgTf,gamT,betT,
        bqf,bkf,bvf,bzrf,bhf,bgf2,alphaf,weightf,
        d_in[1],d_in[3],d_in[5],d_in[12],d_in[18],d_in[19],
        d_in[2],d_in[4],d_in[6],d_in[15],d_in[17],d_in[13],
        d_in[7],d_in[11],flag);
    prep_msg_kernel<<<C_,C_,0,stream>>>(W2f,b2l,b2r,d_in[10],d_in[8],d_in[9],flag);
    prep_w1tf<<<64,256,0,stream>>>(w2T,W2f);
    prep_w3t<<<(256*2304+255)/256,256,0,stream>>>(wzrT,d_in[14],flag,256);
    prep_w3t<<<(128*2304+255)/256,256,0,stream>>>(whT,d_in[16],flag,128);

    for(int it=0; it<3; ++it){
        attn2<<<SBn/2,512,0,stream>>>(b2,b1,wqT,wkT,wvT,bqf,bkf,bvf,
                                      w2T,b2l,b2r,wgTf,bgf2,alphaf,weightf);
        gru_fused<<<SBn,512,0,stream>>>(b1,b2,b1,wzrT,bzrf,whT,bhf,gamT,betT);
    }
    finalT_kernel<<<SBn,256,0,stream>>>(d_out,b1,flag);
}